// Round 1
// baseline (575.052 us; speedup 1.0000x reference)
//
#include <hip/hip_runtime.h>
#include <math.h>

#define NSC 64
#define NVC 64
#define EMB 32
#define NTYPES 20
#define NB 8
#define RH 16
#define LAYERS 2
#define CUTV 3.5f
#define HSTEP 0.1f

// ---------------------------------------------------------------------------
// Exact LAPACK-style Householder QR of Ku^T (64x2) -> Q (64x2), matching
// jnp/np.linalg.qr sign conventions (sgeqr2 + sorg2r).
// ---------------------------------------------------------------------------
__global__ void qr_kernel(const float* __restrict__ Ku, float* __restrict__ Q)
{
  if (threadIdx.x != 0 || blockIdx.x != 0) return;
  float A0[64], A1[64], v0[64], v1[64], t1[64];
  for (int i = 0; i < 64; ++i) { A0[i] = Ku[i]; A1[i] = Ku[64 + i]; }
  // Householder reflector for column 0
  float alpha = A0[0];
  float xn2 = 0.f;
  for (int i = 1; i < 64; ++i) xn2 += A0[i] * A0[i];
  float beta0 = -copysignf(sqrtf(alpha * alpha + xn2), alpha);
  float tau0 = (beta0 - alpha) / beta0;
  float inv0 = 1.f / (alpha - beta0);
  v0[0] = 1.f;
  for (int i = 1; i < 64; ++i) v0[i] = A0[i] * inv0;
  // apply H0 to column 1
  float w = 0.f;
  for (int i = 0; i < 64; ++i) w += v0[i] * A1[i];
  for (int i = 0; i < 64; ++i) A1[i] -= tau0 * w * v0[i];
  // Householder reflector for column 1 (rows 1..63)
  float alpha1 = A1[1];
  float xn2b = 0.f;
  for (int i = 2; i < 64; ++i) xn2b += A1[i] * A1[i];
  float beta1 = -copysignf(sqrtf(alpha1 * alpha1 + xn2b), alpha1);
  float tau1 = (beta1 - alpha1) / beta1;
  float inv1 = 1.f / (alpha1 - beta1);
  v1[0] = 0.f; v1[1] = 1.f;
  for (int i = 2; i < 64; ++i) v1[i] = A1[i] * inv1;
  // Q = H0 H1 [e0 e1]
  for (int i = 0; i < 64; ++i) t1[i] = ((i == 1) ? 1.f : 0.f) - tau1 * v1[i];
  float d = 0.f;
  for (int i = 0; i < 64; ++i) d += v0[i] * t1[i];
  for (int i = 0; i < 64; ++i) {
    float q0 = ((i == 0) ? 1.f : 0.f) - tau0 * v0[i];
    float q1 = t1[i] - tau0 * d * v0[i];
    Q[i * 2 + 0] = q0;
    Q[i * 2 + 1] = q1;
  }
}

// ---------------------------------------------------------------------------
// y_s = 0, y_v[n,h,d] = x_v[n,0,d]*Q[h,0] + x_v[n,1,d]*Q[h,1]; zero counts.
// ---------------------------------------------------------------------------
__global__ void init_state(const float* __restrict__ x, const float* __restrict__ Qm,
                           float* __restrict__ ys0, float* __restrict__ yv0,
                           int* __restrict__ cnt, int n)
{
  const int i = blockIdx.x * 256 + threadIdx.x;
  const int node = i >> 6, lane = i & 63;
  if (node < n) {
    ys0[i] = 0.f;
    const float q0 = Qm[lane * 2 + 0], q1 = Qm[lane * 2 + 1];
    const float* xp = x + (size_t)node * 6;
    float* yp = yv0 + (size_t)node * 192 + lane * 3;
    yp[0] = xp[0] * q0 + xp[3] * q1;
    yp[1] = xp[1] * q0 + xp[4] * q1;
    yp[2] = xp[2] * q0 + xp[5] * q1;
  }
  if (i < n) cnt[i] = 0;
}

__global__ void hist_kernel(const int* __restrict__ edst, int* __restrict__ cnt, int m)
{
  const int e = blockIdx.x * 256 + threadIdx.x;
  if (e < m) atomicAdd(&cnt[edst[e]], 1);
}

// Single-block exclusive scan of counts (reads cnt, writes off[0..n] and resets
// cnt[i] = off[i] so the scatter pass can atomically bump it).
__global__ void scan_kernel(int* cnt, int* off, int n)
{
  __shared__ int lds[1024];
  const int t = threadIdx.x;
  const int CH = (n + 1023) >> 10;   // <= 16 for n <= 16384
  const int base = t * CH;
  int local[16];
  int run = 0;
  for (int j = 0; j < CH; ++j) {
    int v = (base + j < n) ? cnt[base + j] : 0;
    local[j] = run;
    run += v;
  }
  lds[t] = run;
  __syncthreads();
  for (int s = 1; s < 1024; s <<= 1) {
    int v = (t >= s) ? lds[t - s] : 0;
    __syncthreads();
    lds[t] += v;
    __syncthreads();
  }
  const int excl = lds[t] - run;
  for (int j = 0; j < CH; ++j) {
    if (base + j < n) {
      int o = excl + local[j];
      off[base + j] = o;
      cnt[base + j] = o;   // becomes the scatter cursor
    }
  }
  if (t == 1023) off[n] = lds[1023];
}

__global__ void scatter_kernel(const int* __restrict__ edst, int* __restrict__ cursor,
                               int* __restrict__ csr, int m)
{
  const int e = blockIdx.x * 256 + threadIdx.x;
  if (e < m) {
    int p = atomicAdd(&cursor[edst[e]], 1);
    csr[p] = e;
  }
}

// ---------------------------------------------------------------------------
// Per-(layer,type) folded self-connection weights:
//   Ws[lt][s][o] = sum_e embed[t,e] * W_sc_s[l,s,e,o]   (64x128)
//   Wv[lt][v][u] = sum_e embed[t,e] * W_sc_v[l,v,e,u]   (64x64)
// ---------------------------------------------------------------------------
__global__ void type_weights(const float* __restrict__ embed,
                             const float* __restrict__ Wss,
                             const float* __restrict__ Wsv,
                             float* __restrict__ Ws, float* __restrict__ Wv)
{
  const int bid = blockIdx.x;         // l*NTYPES + t
  const int l = bid / NTYPES, t = bid % NTYPES;
  __shared__ float a[EMB];
  if (threadIdx.x < EMB) a[threadIdx.x] = embed[t * EMB + threadIdx.x];
  __syncthreads();
  for (int p = threadIdx.x; p < 64 * 128; p += 256) {
    const int s = p >> 7, o = p & 127;
    const float* wp = Wss + ((size_t)(l * 64 + s) * EMB) * 128 + o;
    float acc = 0.f;
    #pragma unroll
    for (int e = 0; e < EMB; ++e) acc = fmaf(a[e], wp[e * 128], acc);
    Ws[(size_t)bid * 8192 + p] = acc;
  }
  for (int p = threadIdx.x; p < 64 * 64; p += 256) {
    const int v = p >> 6, u = p & 63;
    const float* wp = Wsv + ((size_t)(l * 64 + v) * EMB) * 64 + u;
    float acc = 0.f;
    #pragma unroll
    for (int e = 0; e < EMB; ++e) acc = fmaf(a[e], wp[e * 64], acc);
    Wv[(size_t)bid * 4096 + p] = acc;
  }
}

// ---------------------------------------------------------------------------
// Per-edge geometry + first MLP layer. egeo[e] = [eaX,eaY,eaZ,pad, hid0..15]
// ---------------------------------------------------------------------------
__global__ void edge_geom(const float* __restrict__ xv,
                          const int* __restrict__ esrc, const int* __restrict__ edst,
                          const float* __restrict__ Wr1l, const float* __restrict__ br1l,
                          float* __restrict__ egeo, int m)
{
  const int e = blockIdx.x * 256 + threadIdx.x;
  if (e >= m) return;
  const int s = esrc[e], d = edst[e];
  const float ex = xv[(size_t)s * 6 + 0] - xv[(size_t)d * 6 + 0];
  const float ey = xv[(size_t)s * 6 + 1] - xv[(size_t)d * 6 + 1];
  const float ez = xv[(size_t)s * 6 + 2] - xv[(size_t)d * 6 + 2];
  const float len = sqrtf(ex * ex + ey * ey + ez * ez);
  const float invl = 1.f / len;
  const float u = len * (1.f / CUTV);
  const float vv = 2.f * (u - 1.f);
  float cut = 0.5f * (1.f - cosf((float)M_PI * vv));
  cut = (vv > 0.f) ? 0.f : cut;
  cut = (vv < -1.f) ? 1.f : cut;
  const float cc = cut * 1.7320508075688772f * invl;
  float4* outp = (float4*)(egeo + (size_t)e * 20);
  outp[0] = make_float4(cc * ex, cc * ey, cc * ez, 0.f);
  float bess[NB];
  const float amp = 2.1380899352993948f * invl;  // sqrt(2/CUT)*sqrt(NB)
  const float arg = (float)M_PI * len * (1.f / CUTV);
  #pragma unroll
  for (int k = 0; k < NB; ++k) bess[k] = amp * sinf(arg * (float)(k + 1));
  float hid[RH];
  #pragma unroll
  for (int j = 0; j < RH; ++j) {
    float h = br1l[j];
    #pragma unroll
    for (int k = 0; k < NB; ++k) h = fmaf(bess[k], Wr1l[k * RH + j], h);
    hid[j] = h / (1.f + expf(-h));   // silu
  }
  outp[1] = make_float4(hid[0], hid[1], hid[2], hid[3]);
  outp[2] = make_float4(hid[4], hid[5], hid[6], hid[7]);
  outp[3] = make_float4(hid[8], hid[9], hid[10], hid[11]);
  outp[4] = make_float4(hid[12], hid[13], hid[14], hid[15]);
}

// ---------------------------------------------------------------------------
// One wave per destination node: accumulate messages over incoming edges in
// registers (lane = channel), then fused self-connection matvecs + state
// update + x_v projection (wave butterfly reduce).
// ---------------------------------------------------------------------------
__global__ __launch_bounds__(256, 2) void gather_update(
    const int* __restrict__ off, const int* __restrict__ csr,
    const int* __restrict__ esrc, const float* __restrict__ egeo,
    const float* __restrict__ ys_in, const float* __restrict__ yv_in,
    const int* __restrict__ nattr,
    const float* __restrict__ Ws, const float* __restrict__ Wv,
    const float* __restrict__ Wr2l, const float* __restrict__ br2l,
    const float* __restrict__ Qm,
    float* __restrict__ ys_out, float* __restrict__ yv_out,
    float* __restrict__ xv_out, int n)
{
  const int lane = threadIdx.x & 63;
  const int node = blockIdx.x * 4 + (threadIdx.x >> 6);
  if (node >= n) return;

  // Wr2 columns for this lane's four output channels, kept in VGPRs.
  float wr2A[RH], wr2B[RH], wr2C[RH], wr2D[RH];
  #pragma unroll
  for (int j = 0; j < RH; ++j) {
    const float* r = Wr2l + j * 256 + lane;
    wr2A[j] = r[0]; wr2B[j] = r[64]; wr2C[j] = r[128]; wr2D[j] = r[192];
  }
  const float bA = br2l[lane], bB = br2l[64 + lane],
              bC = br2l[128 + lane], bD = br2l[192 + lane];

  float aS1 = 0.f, aS2 = 0.f, aV0 = 0.f, aV1 = 0.f, aV2 = 0.f;
  const int k0 = off[node], k1 = off[node + 1];
  for (int k = k0; k < k1; ++k) {
    const int e = csr[k];
    const int src = esrc[e];
    const float4* g = (const float4*)(egeo + (size_t)e * 20);
    const float4 g0 = g[0], g1 = g[1], g2 = g[2], g3 = g[3], g4 = g[4];
    const float hid[RH] = { g1.x, g1.y, g1.z, g1.w, g2.x, g2.y, g2.z, g2.w,
                            g3.x, g3.y, g3.z, g3.w, g4.x, g4.y, g4.z, g4.w };
    float wA = bA, wB = bB, wC = bC, wD = bD;
    #pragma unroll
    for (int j = 0; j < RH; ++j) {
      wA = fmaf(hid[j], wr2A[j], wA);
      wB = fmaf(hid[j], wr2B[j], wB);
      wC = fmaf(hid[j], wr2C[j], wC);
      wD = fmaf(hid[j], wr2D[j], wD);
    }
    const float s = ys_in[(size_t)src * 64 + lane];
    const float* vp = yv_in + (size_t)src * 192 + lane * 3;
    const float vx = vp[0], vy = vp[1], vz = vp[2];
    const float dt = vx * g0.x + vy * g0.y + vz * g0.z;
    aS1 = fmaf(wB, dt, aS1);
    aS2 = fmaf(wD, dt, aS2);
    const float t = wA * s;
    const float cx = vy * g0.z - vz * g0.y;
    const float cy = vz * g0.x - vx * g0.z;
    const float cz = vx * g0.y - vy * g0.x;
    aV0 += t * g0.x + wC * cx;
    aV1 += t * g0.y + wC * cy;
    aV2 += t * g0.z + wC * cz;
  }
  const float inv_deg = 0.17677669529663687f;  // 1/sqrt(32)

  // node phase: sc_s / sc_v matvecs with per-type folded weights
  const int ty = nattr[node];
  const float* WsT = Ws + (size_t)ty * 8192;
  const float* WvT = Wv + (size_t)ty * 4096;
  const float ys_own = ys_in[(size_t)node * 64 + lane];
  const float* vop = yv_in + (size_t)node * 192 + lane * 3;
  const float v0x = vop[0], v0y = vop[1], v0z = vop[2];
  float oS1 = 0.f, oS2 = 0.f, oV0 = 0.f, oV1 = 0.f, oV2 = 0.f;
  for (int s2 = 0; s2 < 64; ++s2) {
    const float yss = __shfl(ys_own, s2, 64);
    const float b0 = __shfl(v0x, s2, 64);
    const float b1 = __shfl(v0y, s2, 64);
    const float b2 = __shfl(v0z, s2, 64);
    const float wsA = WsT[s2 * 128 + lane];
    const float wsB = WsT[s2 * 128 + 64 + lane];
    const float wvv = WvT[s2 * 64 + lane];
    oS1 = fmaf(yss, wsA, oS1);
    oS2 = fmaf(yss, wsB, oS2);
    oV0 = fmaf(b0, wvv, oV0);
    oV1 = fmaf(b1, wvv, oV1);
    oV2 = fmaf(b2, wvv, oV2);
  }
  const float outS1 = oS1 + aS1 * inv_deg;
  const float outS2 = oS2 + aS2 * inv_deg;
  const float sig1 = 1.f / (1.f + expf(-outS1));
  const float gate = 1.f / (1.f + expf(-outS2));
  const float ysn = ys_own + HSTEP * outS1 * sig1;
  const float gf = HSTEP * gate;
  const float yvn0 = v0x + gf * (oV0 + aV0 * inv_deg);
  const float yvn1 = v0y + gf * (oV1 + aV1 * inv_deg);
  const float yvn2 = v0z + gf * (oV2 + aV2 * inv_deg);
  ys_out[(size_t)node * 64 + lane] = ysn;
  float* yop = yv_out + (size_t)node * 192 + lane * 3;
  yop[0] = yvn0; yop[1] = yvn1; yop[2] = yvn2;

  // x_v[n,c,d] = sum_h yvn[h,d] * Q[h,c]  -> butterfly reduce 6 scalars
  const float q0 = Qm[lane * 2 + 0], q1 = Qm[lane * 2 + 1];
  float pr[6] = { yvn0 * q0, yvn1 * q0, yvn2 * q0,
                  yvn0 * q1, yvn1 * q1, yvn2 * q1 };
  #pragma unroll
  for (int mm = 1; mm < 64; mm <<= 1) {
    #pragma unroll
    for (int i = 0; i < 6; ++i) pr[i] += __shfl_xor(pr[i], mm, 64);
  }
  if (lane == 0) {
    #pragma unroll
    for (int i = 0; i < 6; ++i) xv_out[(size_t)node * 6 + i] = pr[i];
  }
}

// ---------------------------------------------------------------------------
extern "C" void kernel_launch(void* const* d_in, const int* in_sizes, int n_in,
                              void* d_out, int out_size, void* d_ws, size_t ws_size,
                              hipStream_t stream)
{
  const float* x     = (const float*)d_in[0];
  const int*   nattr = (const int*)d_in[2];
  const int*   esrc  = (const int*)d_in[3];
  const int*   edst  = (const int*)d_in[4];
  const float* embed = (const float*)d_in[5];
  const float* Ku    = (const float*)d_in[6];
  const float* Wss   = (const float*)d_in[7];
  const float* Wsv   = (const float*)d_in[8];
  const float* Wr1   = (const float*)d_in[9];
  const float* br1   = (const float*)d_in[10];
  const float* Wr2   = (const float*)d_in[11];
  const float* br2   = (const float*)d_in[12];
  const int n = in_sizes[0] / 6;
  const int m = in_sizes[3];

  char* p = (char*)d_ws;
  auto alloc = [&](size_t bytes) -> char* {
    char* r = p;
    p += (bytes + 255) & ~(size_t)255;
    return r;
  };
  int*   off    = (int*)alloc((size_t)(n + 1) * 4);
  int*   cursor = (int*)alloc((size_t)n * 4);
  int*   csr    = (int*)alloc((size_t)m * 4);
  float* Q      = (float*)alloc(128 * 4);
  float* Ws     = (float*)alloc((size_t)LAYERS * NTYPES * 64 * 128 * 4);
  float* Wv     = (float*)alloc((size_t)LAYERS * NTYPES * 64 * 64 * 4);
  float* ys0    = (float*)alloc((size_t)n * 64 * 4);
  float* ys1    = (float*)alloc((size_t)n * 64 * 4);
  float* yv0    = (float*)alloc((size_t)n * 192 * 4);
  float* yv1    = (float*)alloc((size_t)n * 192 * 4);
  float* xvb    = (float*)alloc((size_t)n * 6 * 4);
  float* egeo   = (float*)alloc((size_t)m * 20 * 4);

  qr_kernel<<<1, 64, 0, stream>>>(Ku, Q);
  init_state<<<(n * 64 + 255) / 256, 256, 0, stream>>>(x, Q, ys0, yv0, cursor, n);
  hist_kernel<<<(m + 255) / 256, 256, 0, stream>>>(edst, cursor, m);
  scan_kernel<<<1, 1024, 0, stream>>>(cursor, off, n);
  scatter_kernel<<<(m + 255) / 256, 256, 0, stream>>>(edst, cursor, csr, m);
  type_weights<<<LAYERS * NTYPES, 256, 0, stream>>>(embed, Wss, Wsv, Ws, Wv);

  const float* xv_cur = x;
  const float* ys_cur = ys0;
  const float* yv_cur = yv0;
  float* ys_nxt = ys1;
  float* yv_nxt = yv1;
  for (int l = 0; l < LAYERS; ++l) {
    edge_geom<<<(m + 255) / 256, 256, 0, stream>>>(
        xv_cur, esrc, edst, Wr1 + l * NB * RH, br1 + l * RH, egeo, m);
    float* xv_out = (l == LAYERS - 1) ? (float*)d_out : xvb;
    gather_update<<<(n + 3) / 4, 256, 0, stream>>>(
        off, csr, esrc, egeo, ys_cur, yv_cur, nattr,
        Ws + (size_t)l * NTYPES * 8192, Wv + (size_t)l * NTYPES * 4096,
        Wr2 + l * RH * 256, br2 + l * 256, Q,
        ys_nxt, yv_nxt, xv_out, n);
    xv_cur = xv_out;
    const float* ts = ys_cur; ys_cur = ys_nxt; ys_nxt = (float*)ts;
    const float* tv = yv_cur; yv_cur = yv_nxt; yv_nxt = (float*)tv;
  }
}

// Round 2
// 395.520 us; speedup vs baseline: 1.4539x; 1.4539x over previous
//
#include <hip/hip_runtime.h>
#include <math.h>

#define NSC 64
#define NVC 64
#define EMB 32
#define NTYPES 20
#define NB 8
#define RH 16
#define LAYERS 2
#define CUTV 3.5f
#define HSTEP 0.1f

// ---------------------------------------------------------------------------
// Exact LAPACK-style Householder QR of Ku^T (64x2) -> Q (64x2), matching
// jnp/np.linalg.qr sign conventions (sgeqr2 + sorg2r).
// ---------------------------------------------------------------------------
__global__ void qr_kernel(const float* __restrict__ Ku, float* __restrict__ Q)
{
  if (threadIdx.x != 0 || blockIdx.x != 0) return;
  float A0[64], A1[64], v0[64], v1[64], t1[64];
  for (int i = 0; i < 64; ++i) { A0[i] = Ku[i]; A1[i] = Ku[64 + i]; }
  // Householder reflector for column 0
  float alpha = A0[0];
  float xn2 = 0.f;
  for (int i = 1; i < 64; ++i) xn2 += A0[i] * A0[i];
  float beta0 = -copysignf(sqrtf(alpha * alpha + xn2), alpha);
  float tau0 = (beta0 - alpha) / beta0;
  float inv0 = 1.f / (alpha - beta0);
  v0[0] = 1.f;
  for (int i = 1; i < 64; ++i) v0[i] = A0[i] * inv0;
  // apply H0 to column 1
  float w = 0.f;
  for (int i = 0; i < 64; ++i) w += v0[i] * A1[i];
  for (int i = 0; i < 64; ++i) A1[i] -= tau0 * w * v0[i];
  // Householder reflector for column 1 (rows 1..63)
  float alpha1 = A1[1];
  float xn2b = 0.f;
  for (int i = 2; i < 64; ++i) xn2b += A1[i] * A1[i];
  float beta1 = -copysignf(sqrtf(alpha1 * alpha1 + xn2b), alpha1);
  float tau1 = (beta1 - alpha1) / beta1;
  float inv1 = 1.f / (alpha1 - beta1);
  v1[0] = 0.f; v1[1] = 1.f;
  for (int i = 2; i < 64; ++i) v1[i] = A1[i] * inv1;
  // Q = H0 H1 [e0 e1]
  for (int i = 0; i < 64; ++i) t1[i] = ((i == 1) ? 1.f : 0.f) - tau1 * v1[i];
  float d = 0.f;
  for (int i = 0; i < 64; ++i) d += v0[i] * t1[i];
  for (int i = 0; i < 64; ++i) {
    float q0 = ((i == 0) ? 1.f : 0.f) - tau0 * v0[i];
    float q1 = t1[i] - tau0 * d * v0[i];
    Q[i * 2 + 0] = q0;
    Q[i * 2 + 1] = q1;
  }
}

// ---------------------------------------------------------------------------
// y_s = 0, y_v[n,h,d] = x_v[n,0,d]*Q[h,0] + x_v[n,1,d]*Q[h,1]; zero counts.
// ---------------------------------------------------------------------------
__global__ void init_state(const float* __restrict__ x, const float* __restrict__ Qm,
                           float* __restrict__ ys0, float* __restrict__ yv0,
                           int* __restrict__ cnt, int n)
{
  const int i = blockIdx.x * 256 + threadIdx.x;
  const int node = i >> 6, lane = i & 63;
  if (node < n) {
    ys0[i] = 0.f;
    const float q0 = Qm[lane * 2 + 0], q1 = Qm[lane * 2 + 1];
    const float* xp = x + (size_t)node * 6;
    float* yp = yv0 + (size_t)node * 192 + lane * 3;
    yp[0] = xp[0] * q0 + xp[3] * q1;
    yp[1] = xp[1] * q0 + xp[4] * q1;
    yp[2] = xp[2] * q0 + xp[5] * q1;
  }
  if (i < n) cnt[i] = 0;
}

__global__ void hist_kernel(const int* __restrict__ edst, int* __restrict__ cnt, int m)
{
  const int e = blockIdx.x * 256 + threadIdx.x;
  if (e < m) atomicAdd(&cnt[edst[e]], 1);
}

// Single-block exclusive scan of counts (reads cnt, writes off[0..n] and resets
// cnt[i] = off[i] so the scatter pass can atomically bump it).
__global__ void scan_kernel(int* cnt, int* off, int n)
{
  __shared__ int lds[1024];
  const int t = threadIdx.x;
  const int CH = (n + 1023) >> 10;   // <= 16 for n <= 16384
  const int base = t * CH;
  int local[16];
  int run = 0;
  for (int j = 0; j < CH; ++j) {
    int v = (base + j < n) ? cnt[base + j] : 0;
    local[j] = run;
    run += v;
  }
  lds[t] = run;
  __syncthreads();
  for (int s = 1; s < 1024; s <<= 1) {
    int v = (t >= s) ? lds[t - s] : 0;
    __syncthreads();
    lds[t] += v;
    __syncthreads();
  }
  const int excl = lds[t] - run;
  for (int j = 0; j < CH; ++j) {
    if (base + j < n) {
      int o = excl + local[j];
      off[base + j] = o;
      cnt[base + j] = o;   // becomes the scatter cursor
    }
  }
  if (t == 1023) off[n] = lds[1023];
}

__global__ void scatter_kernel(const int* __restrict__ edst, int* __restrict__ cursor,
                               int* __restrict__ csr, int m)
{
  const int e = blockIdx.x * 256 + threadIdx.x;
  if (e < m) {
    int p = atomicAdd(&cursor[edst[e]], 1);
    csr[p] = e;
  }
}

// ---------------------------------------------------------------------------
// Per-(layer,type) folded self-connection weights, fully output-parallel:
//   Ws[lt][s][o] = sum_e embed[t,e] * W_sc_s[l,s,e,o]   (64x128 per lt)
//   Wv[lt][v][u] = sum_e embed[t,e] * W_sc_v[l,v,e,u]   (64x64 per lt)
// One thread per output element; weight reads are lane-coalesced, embed
// reads are wave-uniform broadcasts.
// ---------------------------------------------------------------------------
__global__ void type_weights(const float* __restrict__ embed,
                             const float* __restrict__ Wss,
                             const float* __restrict__ Wsv,
                             float* __restrict__ Ws, float* __restrict__ Wv,
                             int total_s, int total_v)
{
  const int i = blockIdx.x * 256 + threadIdx.x;
  if (i < total_s) {
    const int bid = i >> 13;          // l*NTYPES + t
    const int p = i & 8191;
    const int l = bid / NTYPES, t = bid % NTYPES;
    const int s = p >> 7, o = p & 127;
    const float* ar = embed + t * EMB;
    const float* wp = Wss + ((size_t)(l * 64 + s) * EMB) * 128 + o;
    float acc = 0.f;
    #pragma unroll
    for (int e = 0; e < EMB; ++e) acc = fmaf(ar[e], wp[e * 128], acc);
    Ws[i] = acc;
  } else {
    const int j = i - total_s;
    if (j < total_v) {
      const int bid = j >> 12;        // l*NTYPES + t
      const int p = j & 4095;
      const int l = bid / NTYPES, t = bid % NTYPES;
      const int v = p >> 6, u = p & 63;
      const float* ar = embed + t * EMB;
      const float* wp = Wsv + ((size_t)(l * 64 + v) * EMB) * 64 + u;
      float acc = 0.f;
      #pragma unroll
      for (int e = 0; e < EMB; ++e) acc = fmaf(ar[e], wp[e * 64], acc);
      Wv[j] = acc;
    }
  }
}

// ---------------------------------------------------------------------------
// Per-edge geometry + first MLP layer. egeo[e] = [eaX,eaY,eaZ,pad, hid0..15]
// ---------------------------------------------------------------------------
__global__ void edge_geom(const float* __restrict__ xv,
                          const int* __restrict__ esrc, const int* __restrict__ edst,
                          const float* __restrict__ Wr1l, const float* __restrict__ br1l,
                          float* __restrict__ egeo, int m)
{
  const int e = blockIdx.x * 256 + threadIdx.x;
  if (e >= m) return;
  const int s = esrc[e], d = edst[e];
  const float ex = xv[(size_t)s * 6 + 0] - xv[(size_t)d * 6 + 0];
  const float ey = xv[(size_t)s * 6 + 1] - xv[(size_t)d * 6 + 1];
  const float ez = xv[(size_t)s * 6 + 2] - xv[(size_t)d * 6 + 2];
  const float len = sqrtf(ex * ex + ey * ey + ez * ez);
  const float invl = 1.f / len;
  const float u = len * (1.f / CUTV);
  const float vv = 2.f * (u - 1.f);
  float cut = 0.5f * (1.f - cosf((float)M_PI * vv));
  cut = (vv > 0.f) ? 0.f : cut;
  cut = (vv < -1.f) ? 1.f : cut;
  const float cc = cut * 1.7320508075688772f * invl;
  float4* outp = (float4*)(egeo + (size_t)e * 20);
  outp[0] = make_float4(cc * ex, cc * ey, cc * ez, 0.f);
  float bess[NB];
  const float amp = 2.1380899352993948f * invl;  // sqrt(2/CUT)*sqrt(NB)
  const float arg = (float)M_PI * len * (1.f / CUTV);
  #pragma unroll
  for (int k = 0; k < NB; ++k) bess[k] = amp * sinf(arg * (float)(k + 1));
  float hid[RH];
  #pragma unroll
  for (int j = 0; j < RH; ++j) {
    float h = br1l[j];
    #pragma unroll
    for (int k = 0; k < NB; ++k) h = fmaf(bess[k], Wr1l[k * RH + j], h);
    hid[j] = h / (1.f + expf(-h));   // silu
  }
  outp[1] = make_float4(hid[0], hid[1], hid[2], hid[3]);
  outp[2] = make_float4(hid[4], hid[5], hid[6], hid[7]);
  outp[3] = make_float4(hid[8], hid[9], hid[10], hid[11]);
  outp[4] = make_float4(hid[12], hid[13], hid[14], hid[15]);
}

// ---------------------------------------------------------------------------
// One wave per destination node: accumulate messages over incoming edges in
// registers (lane = channel), then fused self-connection matvecs + state
// update + x_v projection (wave butterfly reduce).
// ---------------------------------------------------------------------------
__global__ __launch_bounds__(256, 2) void gather_update(
    const int* __restrict__ off, const int* __restrict__ csr,
    const int* __restrict__ esrc, const float* __restrict__ egeo,
    const float* __restrict__ ys_in, const float* __restrict__ yv_in,
    const int* __restrict__ nattr,
    const float* __restrict__ Ws, const float* __restrict__ Wv,
    const float* __restrict__ Wr2l, const float* __restrict__ br2l,
    const float* __restrict__ Qm,
    float* __restrict__ ys_out, float* __restrict__ yv_out,
    float* __restrict__ xv_out, int n)
{
  const int lane = threadIdx.x & 63;
  const int node = blockIdx.x * 4 + (threadIdx.x >> 6);
  if (node >= n) return;

  // Wr2 columns for this lane's four output channels, kept in VGPRs.
  float wr2A[RH], wr2B[RH], wr2C[RH], wr2D[RH];
  #pragma unroll
  for (int j = 0; j < RH; ++j) {
    const float* r = Wr2l + j * 256 + lane;
    wr2A[j] = r[0]; wr2B[j] = r[64]; wr2C[j] = r[128]; wr2D[j] = r[192];
  }
  const float bA = br2l[lane], bB = br2l[64 + lane],
              bC = br2l[128 + lane], bD = br2l[192 + lane];

  float aS1 = 0.f, aS2 = 0.f, aV0 = 0.f, aV1 = 0.f, aV2 = 0.f;
  const int k0 = off[node], k1 = off[node + 1];
  for (int k = k0; k < k1; ++k) {
    const int e = csr[k];
    const int src = esrc[e];
    const float4* g = (const float4*)(egeo + (size_t)e * 20);
    const float4 g0 = g[0], g1 = g[1], g2 = g[2], g3 = g[3], g4 = g[4];
    const float hid[RH] = { g1.x, g1.y, g1.z, g1.w, g2.x, g2.y, g2.z, g2.w,
                            g3.x, g3.y, g3.z, g3.w, g4.x, g4.y, g4.z, g4.w };
    float wA = bA, wB = bB, wC = bC, wD = bD;
    #pragma unroll
    for (int j = 0; j < RH; ++j) {
      wA = fmaf(hid[j], wr2A[j], wA);
      wB = fmaf(hid[j], wr2B[j], wB);
      wC = fmaf(hid[j], wr2C[j], wC);
      wD = fmaf(hid[j], wr2D[j], wD);
    }
    const float s = ys_in[(size_t)src * 64 + lane];
    const float* vp = yv_in + (size_t)src * 192 + lane * 3;
    const float vx = vp[0], vy = vp[1], vz = vp[2];
    const float dt = vx * g0.x + vy * g0.y + vz * g0.z;
    aS1 = fmaf(wB, dt, aS1);
    aS2 = fmaf(wD, dt, aS2);
    const float t = wA * s;
    const float cx = vy * g0.z - vz * g0.y;
    const float cy = vz * g0.x - vx * g0.z;
    const float cz = vx * g0.y - vy * g0.x;
    aV0 += t * g0.x + wC * cx;
    aV1 += t * g0.y + wC * cy;
    aV2 += t * g0.z + wC * cz;
  }
  const float inv_deg = 0.17677669529663687f;  // 1/sqrt(32)

  // node phase: sc_s / sc_v matvecs with per-type folded weights
  const int ty = nattr[node];
  const float* WsT = Ws + (size_t)ty * 8192;
  const float* WvT = Wv + (size_t)ty * 4096;
  const float ys_own = ys_in[(size_t)node * 64 + lane];
  const float* vop = yv_in + (size_t)node * 192 + lane * 3;
  const float v0x = vop[0], v0y = vop[1], v0z = vop[2];
  float oS1 = 0.f, oS2 = 0.f, oV0 = 0.f, oV1 = 0.f, oV2 = 0.f;
  for (int s2 = 0; s2 < 64; ++s2) {
    const float yss = __shfl(ys_own, s2, 64);
    const float b0 = __shfl(v0x, s2, 64);
    const float b1 = __shfl(v0y, s2, 64);
    const float b2 = __shfl(v0z, s2, 64);
    const float wsA = WsT[s2 * 128 + lane];
    const float wsB = WsT[s2 * 128 + 64 + lane];
    const float wvv = WvT[s2 * 64 + lane];
    oS1 = fmaf(yss, wsA, oS1);
    oS2 = fmaf(yss, wsB, oS2);
    oV0 = fmaf(b0, wvv, oV0);
    oV1 = fmaf(b1, wvv, oV1);
    oV2 = fmaf(b2, wvv, oV2);
  }
  const float outS1 = oS1 + aS1 * inv_deg;
  const float outS2 = oS2 + aS2 * inv_deg;
  const float sig1 = 1.f / (1.f + expf(-outS1));
  const float gate = 1.f / (1.f + expf(-outS2));
  const float ysn = ys_own + HSTEP * outS1 * sig1;
  const float gf = HSTEP * gate;
  const float yvn0 = v0x + gf * (oV0 + aV0 * inv_deg);
  const float yvn1 = v0y + gf * (oV1 + aV1 * inv_deg);
  const float yvn2 = v0z + gf * (oV2 + aV2 * inv_deg);
  ys_out[(size_t)node * 64 + lane] = ysn;
  float* yop = yv_out + (size_t)node * 192 + lane * 3;
  yop[0] = yvn0; yop[1] = yvn1; yop[2] = yvn2;

  // x_v[n,c,d] = sum_h yvn[h,d] * Q[h,c]  -> butterfly reduce 6 scalars
  const float q0 = Qm[lane * 2 + 0], q1 = Qm[lane * 2 + 1];
  float pr[6] = { yvn0 * q0, yvn1 * q0, yvn2 * q0,
                  yvn0 * q1, yvn1 * q1, yvn2 * q1 };
  #pragma unroll
  for (int mm = 1; mm < 64; mm <<= 1) {
    #pragma unroll
    for (int i = 0; i < 6; ++i) pr[i] += __shfl_xor(pr[i], mm, 64);
  }
  if (lane == 0) {
    #pragma unroll
    for (int i = 0; i < 6; ++i) xv_out[(size_t)node * 6 + i] = pr[i];
  }
}

// ---------------------------------------------------------------------------
extern "C" void kernel_launch(void* const* d_in, const int* in_sizes, int n_in,
                              void* d_out, int out_size, void* d_ws, size_t ws_size,
                              hipStream_t stream)
{
  const float* x     = (const float*)d_in[0];
  const int*   nattr = (const int*)d_in[2];
  const int*   esrc  = (const int*)d_in[3];
  const int*   edst  = (const int*)d_in[4];
  const float* embed = (const float*)d_in[5];
  const float* Ku    = (const float*)d_in[6];
  const float* Wss   = (const float*)d_in[7];
  const float* Wsv   = (const float*)d_in[8];
  const float* Wr1   = (const float*)d_in[9];
  const float* br1   = (const float*)d_in[10];
  const float* Wr2   = (const float*)d_in[11];
  const float* br2   = (const float*)d_in[12];
  const int n = in_sizes[0] / 6;
  const int m = in_sizes[3];

  char* p = (char*)d_ws;
  auto alloc = [&](size_t bytes) -> char* {
    char* r = p;
    p += (bytes + 255) & ~(size_t)255;
    return r;
  };
  int*   off    = (int*)alloc((size_t)(n + 1) * 4);
  int*   cursor = (int*)alloc((size_t)n * 4);
  int*   csr    = (int*)alloc((size_t)m * 4);
  float* Q      = (float*)alloc(128 * 4);
  float* Ws     = (float*)alloc((size_t)LAYERS * NTYPES * 64 * 128 * 4);
  float* Wv     = (float*)alloc((size_t)LAYERS * NTYPES * 64 * 64 * 4);
  float* ys0    = (float*)alloc((size_t)n * 64 * 4);
  float* ys1    = (float*)alloc((size_t)n * 64 * 4);
  float* yv0    = (float*)alloc((size_t)n * 192 * 4);
  float* yv1    = (float*)alloc((size_t)n * 192 * 4);
  float* xvb    = (float*)alloc((size_t)n * 6 * 4);
  float* egeo   = (float*)alloc((size_t)m * 20 * 4);

  const int total_s = LAYERS * NTYPES * 64 * 128;
  const int total_v = LAYERS * NTYPES * 64 * 64;

  qr_kernel<<<1, 64, 0, stream>>>(Ku, Q);
  init_state<<<(n * 64 + 255) / 256, 256, 0, stream>>>(x, Q, ys0, yv0, cursor, n);
  hist_kernel<<<(m + 255) / 256, 256, 0, stream>>>(edst, cursor, m);
  scan_kernel<<<1, 1024, 0, stream>>>(cursor, off, n);
  scatter_kernel<<<(m + 255) / 256, 256, 0, stream>>>(edst, cursor, csr, m);
  type_weights<<<(total_s + total_v + 255) / 256, 256, 0, stream>>>(
      embed, Wss, Wsv, Ws, Wv, total_s, total_v);

  const float* xv_cur = x;
  const float* ys_cur = ys0;
  const float* yv_cur = yv0;
  float* ys_nxt = ys1;
  float* yv_nxt = yv1;
  for (int l = 0; l < LAYERS; ++l) {
    edge_geom<<<(m + 255) / 256, 256, 0, stream>>>(
        xv_cur, esrc, edst, Wr1 + l * NB * RH, br1 + l * RH, egeo, m);
    float* xv_out = (l == LAYERS - 1) ? (float*)d_out : xvb;
    gather_update<<<(n + 3) / 4, 256, 0, stream>>>(
        off, csr, esrc, egeo, ys_cur, yv_cur, nattr,
        Ws + (size_t)l * NTYPES * 8192, Wv + (size_t)l * NTYPES * 4096,
        Wr2 + l * RH * 256, br2 + l * 256, Q,
        ys_nxt, yv_nxt, xv_out, n);
    xv_cur = xv_out;
    const float* ts = ys_cur; ys_cur = ys_nxt; ys_nxt = (float*)ts;
    const float* tv = yv_cur; yv_cur = yv_nxt; yv_nxt = (float*)tv;
  }
}